// Round 1
// baseline (1260.233 us; speedup 1.0000x reference)
//
#include <hip/hip_runtime.h>

#define NTOK 49
#define CDIM 384
#define HEADS 12
#define HD 32
#define NWIN 64
#define NQKV 1152
#define SCALE 0.17677669529663687f  // 32^-0.5

typedef __attribute__((ext_vector_type(8))) __bf16 bf16x8;
typedef __attribute__((ext_vector_type(4))) float f32x4;

// workspace offsets (bytes), all 256-aligned
#define OFF_WQKVT   0ull                 // 1152*384 bf16 = 884736
#define OFF_WOUTT   884736ull            // 384*384 bf16  = 294912
#define OFF_ADDEND  1179648ull           // 64*12*49*49 f32 = 7375872
#define OFF_ATTNOUT 8555520ull           // B*49*384 bf16 = 154140672
// total ~155.2 MB

// ---------------- prep kernels ----------------

__global__ void prep_weights(const float* __restrict__ Wqkv, const float* __restrict__ Wout,
                             __bf16* __restrict__ WqkvT, __bf16* __restrict__ WoutT) {
    int idx = blockIdx.x * 256 + threadIdx.x;
    if (idx < NQKV * CDIM) {
        int n = idx / CDIM, k = idx % CDIM;
        WqkvT[idx] = (__bf16)Wqkv[(size_t)k * NQKV + n];
    }
    if (idx < CDIM * CDIM) {
        int n = idx / CDIM, k = idx % CDIM;
        WoutT[idx] = (__bf16)Wout[(size_t)k * CDIM + n];
    }
}

__global__ void prep_addend(const float* __restrict__ rpb, const int* __restrict__ rel,
                            const float* __restrict__ mask, float* __restrict__ addend) {
    int idx = blockIdx.x * 256 + threadIdx.x;
    if (idx >= NWIN * HEADS * NTOK * NTOK) return;
    int mn = idx % (NTOK * NTOK);
    int h  = (idx / (NTOK * NTOK)) % HEADS;
    int w  = idx / (NTOK * NTOK * HEADS);
    addend[idx] = rpb[rel[mn] * HEADS + h] + mask[(size_t)w * NTOK * NTOK + mn];
}

// ---------------- fused qkv + attention ----------------
// one block per window; 512 threads = 8 waves.
// 3 groups of 4 heads: QKV gemm -> LDS, then attention (2 waves/head), attnout -> ws (bf16)

__global__ __launch_bounds__(512) void fused_qkv_attn(
    const float* __restrict__ x, const float* __restrict__ bqkv,
    const __bf16* __restrict__ WqkvT, const float* __restrict__ addend,
    __bf16* __restrict__ attnout)
{
    // LDS: 50176 + 20480 + 20480 + 18432 + 36864 = 146432 B
    __shared__ __attribute__((aligned(16))) __bf16 xs[64][392];     // x in bf16, rows>=49 zeroed
    __shared__ __attribute__((aligned(16))) __bf16 qs[4][64][40];   // q rows scaled, [tok][d]
    __shared__ __attribute__((aligned(16))) __bf16 ks[4][64][40];   // k, [tok][d]
    __shared__ __attribute__((aligned(16))) __bf16 vt[4][32][72];   // v transposed, [d][tok]
    __shared__ __attribute__((aligned(16))) __bf16 ps[4][64][72];   // P (softmax probs), [m][tok]

    const int b   = blockIdx.x;
    const int tid = threadIdx.x;
    const int wave = tid >> 6, lane = tid & 63;
    const int l15 = lane & 15, l4 = lane >> 4;
    const int w = b & (NWIN - 1);

    // ---- phase 0: stage x -> bf16 LDS ----
    const float* xw = x + (size_t)b * NTOK * CDIM;
    for (int i = tid; i < NTOK * CDIM / 4; i += 512) {
        const float4 v = reinterpret_cast<const float4*>(xw)[i];
        int e = i * 4;
        int r = e / CDIM, c = e % CDIM;   // CDIM%4==0: never crosses rows
        xs[r][c]     = (__bf16)v.x;
        xs[r][c + 1] = (__bf16)v.y;
        xs[r][c + 2] = (__bf16)v.z;
        xs[r][c + 3] = (__bf16)v.w;
    }
    for (int i = tid; i < 15 * 392; i += 512) {
        xs[49 + i / 392][i % 392] = (__bf16)0.f;
    }
    __syncthreads();

    for (int g = 0; g < 3; ++g) {
        // ---- QKV gemm for heads 4g..4g+3: 24 n-tiles of 16, 3 per wave ----
        for (int j = 0; j < 3; ++j) {
            int t = wave * 3 + j;             // 0..23
            int hl = t / 6, rem = t % 6;
            int which = rem >> 1, sub = rem & 1;   // which: 0=q 1=k 2=v
            int h = g * 4 + hl;
            int colbase = which * CDIM + h * HD + sub * 16;
            int wcol = colbase + l15;
            const __bf16* bptr = WqkvT + (size_t)wcol * CDIM + l4 * 8;

            f32x4 acc[4] = {};
            for (int kb = 0; kb < 12; ++kb) {
                bf16x8 bf = *reinterpret_cast<const bf16x8*>(bptr + kb * 32);
#pragma unroll
                for (int mt = 0; mt < 4; ++mt) {
                    bf16x8 af = *reinterpret_cast<const bf16x8*>(&xs[mt * 16 + l15][kb * 32 + l4 * 8]);
                    acc[mt] = __builtin_amdgcn_mfma_f32_16x16x32_bf16(af, bf, acc[mt], 0, 0, 0);
                }
            }
            float bias = bqkv[wcol];
            float scl = (which == 0) ? SCALE : 1.0f;
#pragma unroll
            for (int mt = 0; mt < 4; ++mt) {
#pragma unroll
                for (int r = 0; r < 4; ++r) {
                    int row = mt * 16 + l4 * 4 + r;   // token
                    float v = (acc[mt][r] + bias) * scl;
                    __bf16 bv = (__bf16)v;
                    if (which == 0)      qs[hl][row][sub * 16 + l15] = bv;
                    else if (which == 1) ks[hl][row][sub * 16 + l15] = bv;
                    else                 vt[hl][sub * 16 + l15][row] = bv;
                }
            }
        }
        __syncthreads();

        // ---- attention: head hl = wave>>1, row-half = wave&1 ----
        {
            int hl = wave >> 1, half = wave & 1;
            int h = g * 4 + hl;
            const float* add_h = addend + (size_t)(w * HEADS + h) * (NTOK * NTOK);

            // S = q @ k^T  (K = 32 -> one MFMA per 16x16 tile)
            f32x4 s[2][4];
#pragma unroll
            for (int mi = 0; mi < 2; ++mi) {
                int mt = half * 2 + mi;
                bf16x8 af = *reinterpret_cast<const bf16x8*>(&qs[hl][mt * 16 + l15][l4 * 8]);
#pragma unroll
                for (int nt = 0; nt < 4; ++nt) {
                    bf16x8 bf = *reinterpret_cast<const bf16x8*>(&ks[hl][nt * 16 + l15][l4 * 8]);
                    f32x4 z = {};
                    s[mi][nt] = __builtin_amdgcn_mfma_f32_16x16x32_bf16(af, bf, z, 0, 0, 0);
                }
            }

            // + bias/mask, pad, softmax per row, P -> LDS bf16
#pragma unroll
            for (int mi = 0; mi < 2; ++mi) {
                int mt = half * 2 + mi;
#pragma unroll
                for (int r = 0; r < 4; ++r) {
                    int m = mt * 16 + l4 * 4 + r;
                    float vals[4];
#pragma unroll
                    for (int nt = 0; nt < 4; ++nt) {
                        int n = nt * 16 + l15;
                        float sv = s[mi][nt][r];
                        if (n < NTOK) {
                            if (m < NTOK) sv += add_h[m * NTOK + n];
                        } else {
                            sv = -1e30f;
                        }
                        vals[nt] = sv;
                    }
                    float mx = fmaxf(fmaxf(vals[0], vals[1]), fmaxf(vals[2], vals[3]));
                    mx = fmaxf(mx, __shfl_xor(mx, 1));
                    mx = fmaxf(mx, __shfl_xor(mx, 2));
                    mx = fmaxf(mx, __shfl_xor(mx, 4));
                    mx = fmaxf(mx, __shfl_xor(mx, 8));
                    float e0 = __expf(vals[0] - mx);
                    float e1 = __expf(vals[1] - mx);
                    float e2 = __expf(vals[2] - mx);
                    float e3 = __expf(vals[3] - mx);
                    float sum = (e0 + e1) + (e2 + e3);
                    sum += __shfl_xor(sum, 1);
                    sum += __shfl_xor(sum, 2);
                    sum += __shfl_xor(sum, 4);
                    sum += __shfl_xor(sum, 8);
                    float inv = 1.0f / sum;
                    ps[hl][m][0 * 16 + l15] = (__bf16)(e0 * inv);
                    ps[hl][m][1 * 16 + l15] = (__bf16)(e1 * inv);
                    ps[hl][m][2 * 16 + l15] = (__bf16)(e2 * inv);
                    ps[hl][m][3 * 16 + l15] = (__bf16)(e3 * inv);
                }
            }

            // PV: out[m][d] = sum_tok P[m][tok] * v[tok][d]
            f32x4 o[2][2] = {};
#pragma unroll
            for (int mi = 0; mi < 2; ++mi) {
                int mt = half * 2 + mi;
#pragma unroll
                for (int kb = 0; kb < 2; ++kb) {
                    bf16x8 af = *reinterpret_cast<const bf16x8*>(&ps[hl][mt * 16 + l15][kb * 32 + l4 * 8]);
#pragma unroll
                    for (int nd = 0; nd < 2; ++nd) {
                        bf16x8 bf = *reinterpret_cast<const bf16x8*>(&vt[hl][nd * 16 + l15][kb * 32 + l4 * 8]);
                        o[mi][nd] = __builtin_amdgcn_mfma_f32_16x16x32_bf16(af, bf, o[mi][nd], 0, 0, 0);
                    }
                }
            }
            // store attn-out (bf16) [b][tok][h*32+d]
#pragma unroll
            for (int mi = 0; mi < 2; ++mi) {
                int mt = half * 2 + mi;
#pragma unroll
                for (int nd = 0; nd < 2; ++nd) {
                    int col = h * HD + nd * 16 + l15;
#pragma unroll
                    for (int r = 0; r < 4; ++r) {
                        int tok = mt * 16 + l4 * 4 + r;
                        if (tok < NTOK)
                            attnout[((size_t)b * NTOK + tok) * CDIM + col] = (__bf16)o[mi][nd][r];
                    }
                }
            }
        }
        __syncthreads();
    }
}

// ---------------- out projection: [M=B*49, 384] @ [384,384] + b ----------------
// block: 64 rows, 256 threads = 4 waves; wave w covers n-tiles 6w..6w+5

__global__ __launch_bounds__(256) void out_proj(
    const __bf16* __restrict__ A, const __bf16* __restrict__ WoutT,
    const float* __restrict__ bout, float* __restrict__ out)
{
    __shared__ __attribute__((aligned(16))) __bf16 as[64][392];
    const int blk = blockIdx.x, tid = threadIdx.x;
    const int wave = tid >> 6, lane = tid & 63;
    const int l15 = lane & 15, l4 = lane >> 4;

    const __bf16* Ab = A + (size_t)blk * 64 * CDIM;
    for (int i = tid; i < 64 * CDIM / 8; i += 256) {
        int e = i * 8;
        int r = e / CDIM, c = e % CDIM;
        *reinterpret_cast<int4*>(&as[r][c]) = reinterpret_cast<const int4*>(Ab)[i];
    }
    __syncthreads();

    f32x4 acc[6][4] = {};
    for (int kb = 0; kb < 12; ++kb) {
        bf16x8 af[4];
#pragma unroll
        for (int mt = 0; mt < 4; ++mt)
            af[mt] = *reinterpret_cast<const bf16x8*>(&as[mt * 16 + l15][kb * 32 + l4 * 8]);
#pragma unroll
        for (int j = 0; j < 6; ++j) {
            int col = (wave * 6 + j) * 16 + l15;
            bf16x8 bf = *reinterpret_cast<const bf16x8*>(WoutT + (size_t)col * CDIM + kb * 32 + l4 * 8);
#pragma unroll
            for (int mt = 0; mt < 4; ++mt)
                acc[j][mt] = __builtin_amdgcn_mfma_f32_16x16x32_bf16(af[mt], bf, acc[j][mt], 0, 0, 0);
        }
    }
#pragma unroll
    for (int j = 0; j < 6; ++j) {
        int col = (wave * 6 + j) * 16 + l15;
        float bias = bout[col];
#pragma unroll
        for (int mt = 0; mt < 4; ++mt) {
#pragma unroll
            for (int r = 0; r < 4; ++r) {
                size_t row = (size_t)blk * 64 + mt * 16 + l4 * 4 + r;
                out[row * CDIM + col] = acc[j][mt][r] + bias;
            }
        }
    }
}

// ---------------- launch ----------------

extern "C" void kernel_launch(void* const* d_in, const int* in_sizes, int n_in,
                              void* d_out, int out_size, void* d_ws, size_t ws_size,
                              hipStream_t stream) {
    (void)n_in; (void)out_size; (void)ws_size;
    const float* x    = (const float*)d_in[0];
    const float* mask = (const float*)d_in[1];
    const float* Wqkv = (const float*)d_in[2];
    const float* bqkv = (const float*)d_in[3];
    const float* Wout = (const float*)d_in[4];
    const float* bout = (const float*)d_in[5];
    const float* rpb  = (const float*)d_in[6];
    const int*   rel  = (const int*)d_in[7];

    const int B = in_sizes[0] / (NTOK * CDIM);   // 4096

    char* ws = (char*)d_ws;
    __bf16* WqkvT   = (__bf16*)(ws + OFF_WQKVT);
    __bf16* WoutT   = (__bf16*)(ws + OFF_WOUTT);
    float*  addend  = (float*)(ws + OFF_ADDEND);
    __bf16* attnout = (__bf16*)(ws + OFF_ATTNOUT);
    float*  out     = (float*)d_out;

    prep_weights<<<(NQKV * CDIM + 255) / 256, 256, 0, stream>>>(Wqkv, Wout, WqkvT, WoutT);
    prep_addend<<<(NWIN * HEADS * NTOK * NTOK + 255) / 256, 256, 0, stream>>>(rpb, rel, mask, addend);
    fused_qkv_attn<<<B, 512, 0, stream>>>(x, bqkv, WqkvT, addend, attnout);
    out_proj<<<(B * NTOK) / 64, 256, 0, stream>>>(attnout, WoutT, bout, out);
}